// Round 3
// baseline (2900.196 us; speedup 1.0000x reference)
//
#include <hip/hip_runtime.h>
#include <hip/hip_fp16.h>
#include <stdint.h>

#define B_TOTAL 1024
#define T_TOTAL 1024
#define LOG2E 1.44269504088896f

typedef _Float16 f16x2 __attribute__((ext_vector_type(2)));

__device__ __forceinline__ float dot2acc(uint32_t xw, f16x2 w, float acc) {
#if __has_builtin(__builtin_amdgcn_fdot2)
    return __builtin_amdgcn_fdot2(__builtin_bit_cast(f16x2, xw), w, acc, false);
#else
    f16x2 xv = __builtin_bit_cast(f16x2, xw);
    return acc + (float)xv.x * (float)w.x + (float)xv.y * (float)w.y;
#endif
}

__device__ __forceinline__ float dot2w(uint32_t xw, uint32_t ww, float acc) {
    return dot2acc(xw, __builtin_bit_cast(f16x2, ww), acc);
}

__device__ __forceinline__ uint32_t packf2(float a, float b) {
    f16x2 t;
    t.x = (_Float16)a;
    t.y = (_Float16)b;
    return __builtin_bit_cast(uint32_t, t);
}

__device__ __forceinline__ float sigm_(float z) {
    float e = __builtin_amdgcn_exp2f(-LOG2E * z);
    return __builtin_amdgcn_rcpf(1.0f + e);
}
__device__ __forceinline__ float tanh_(float z) {
    float e = __builtin_amdgcn_exp2f((2.0f * LOG2E) * z);
    float r = __builtin_amdgcn_rcpf(1.0f + e);
    return __builtin_fmaf(-2.0f, r, 1.0f);
}

__device__ __forceinline__ void wavebar() {
#if __has_builtin(__builtin_amdgcn_wave_barrier)
    __builtin_amdgcn_wave_barrier();
#endif
}

// ================== producer/consumer LSTM scan, round 3 ==================
// Round-2 failure analysis: waves_per_eu(2) -> VGPR=96; producer's 120-dword
// weight+prefetch set didn't fit, compiler sank weight loads into the loop
// (FETCH_SIZE +88MB of per-step global weight reloads) -> producer-paced at
// ~1700 cy/step. Fixes:
//   (1) W_ih staged to LDS once; producer reads rows per step via b128/b64
//       LDS reads (lane row-stride = ND dwords -> <=3-way bank alias, free-ish).
//       Producer per-lane regs ~50 dwords: no allocator gamble left.
//   (2) Consumer prefetches slot s+1's (flag,data) during step s: the ~130cy
//       LDS poll round-trip leaves the serial critical path; retry only when
//       producer is actually behind.
// Sync protocol identical to round 2 (proven correct): producer writes data
// then flag (per-wave DS ordering = release); consumer reads flag then data.
// Ring [slot][lane][4] f32: producer emits 4 gate pre-activations per lane.
template <int DIN, int H, bool LAYER1, bool STORE_ALL>
__global__ void __launch_bounds__(128) lstm_pc(
    const float* __restrict__ x,              // LAYER1: [B][T][8] f32
    const __half* __restrict__ inbuf,         // layers>1: [T][B][DIN] f16
    const float* __restrict__ wihf, const float* __restrict__ whhf,
    const float* __restrict__ bihf, const float* __restrict__ bhhf,
    const float* __restrict__ wihb, const float* __restrict__ whhb,
    const float* __restrict__ bihb, const float* __restrict__ bhhb,
    __half* __restrict__ outbuf,              // STORE_ALL: [T][B][2H] f16
    float* __restrict__ lasth)                // !STORE_ALL: [B][H] f32
{
    constexpr int GPW    = 64 / H;    // batch groups per wave (3 or 6)
    constexpr int ND     = DIN / 2;   // input dwords (f16 pairs)
    constexpr int NH     = H / 2;     // h dwords
    constexpr int SLOTS  = 16;
    constexpr int HS_DW  = (H == 20) ? 12 : 8;
    constexpr int WIH_DW = 4 * H * ND;   // packed f16x2 dwords of W_ih

    const int dir  = blockIdx.y;
    const int lane = threadIdx.x;
    const int wv   = threadIdx.y;     // 0 = consumer (scan), 1 = producer
    const int g    = lane / H;
    const int j    = lane - g * H;
    const int b    = blockIdx.x * GPW + g;
    const bool valid = (g < GPW) && (b < B_TOTAL);
    const int bs   = valid ? b : (B_TOTAL - 1);

    __shared__ uint32_t wsm[WIH_DW];            // W_ih, f16x2-packed, [row][d]
    __shared__ float    ring[SLOTS][64][4];     // gate pre-activations
    __shared__ int      flags[SLOTS];
    __shared__ int      consprog;
    __shared__ uint32_t hsm[GPW + 1][HS_DW];

    volatile float* vgx   = (volatile float*)&ring[0][0][0];
    volatile int*   vflg  = flags;
    volatile int*   vcons = &consprog;

    // ---- cooperative W_ih staging (both waves) ----
    {
        const float* w_ih = dir ? wihb : wihf;
        for (int idx = wv * 64 + lane; idx < WIH_DW; idx += 128) {
            const int r = idx / ND;
            const int d = idx - r * ND;
            wsm[idx] = packf2(w_ih[r * DIN + 2 * d], w_ih[r * DIN + 2 * d + 1]);
        }
    }
    if (wv == 0) {
        if (lane < SLOTS) flags[lane] = 0;
        if (lane == 0) consprog = -1;
        ((__half*)&hsm[g][0])[j] = __float2half(0.0f);
    }
    __syncthreads();

    const int tstep = dir ? -1 : 1;
    int tt = dir ? (T_TOTAL - 1) : 0;

    if (wv == 1) {
        // ------------------------- producer -------------------------
        const float* b_i = dir ? bihb : bihf;
        const float* b_h = dir ? bhhb : bhhf;
        float bias[4];
#pragma unroll
        for (int q = 0; q < 4; ++q) bias[q] = b_i[q * H + j] + b_h[q * H + j];

        // input dots with weights read from LDS (b128 when row 16B-aligned)
        auto xdots = [&](const uint32_t* xc, float* a) {
#pragma unroll
            for (int q = 0; q < 4; ++q) {
                const int rowbase = (q * H + j) * ND;
                if constexpr (ND % 4 == 0) {
#pragma unroll
                    for (int d = 0; d < ND; d += 4) {
                        uint4 w4 = *(const uint4*)&wsm[rowbase + d];
                        a[q] = dot2w(xc[d],     w4.x, a[q]);
                        a[q] = dot2w(xc[d + 1], w4.y, a[q]);
                        a[q] = dot2w(xc[d + 2], w4.z, a[q]);
                        a[q] = dot2w(xc[d + 3], w4.w, a[q]);
                    }
                } else {
#pragma unroll
                    for (int d = 0; d < ND; d += 2) {
                        uint2 w2 = *(const uint2*)&wsm[rowbase + d];
                        a[q] = dot2w(xc[d],     w2.x, a[q]);
                        a[q] = dot2w(xc[d + 1], w2.y, a[q]);
                    }
                }
            }
        };

        auto emit = [&](int s, const float* a) {
            if (s >= SLOTS) {
                while (*vcons < s - SLOTS) __builtin_amdgcn_s_sleep(2);
            }
            const int slot = s & (SLOTS - 1);
            volatile float* p = vgx + (size_t)slot * 256 + lane * 4;
            p[0] = a[0];
            p[1] = a[1];
            p[2] = a[2];
            p[3] = a[3];
            vflg[slot] = s + 1;   // release: DS ops of one wave complete in order
        };

        if constexpr (LAYER1) {
            const float* xrow = x + (size_t)bs * (T_TOTAL * 8);
            uint32_t xv[8];   // [0..3]=cur, [4..7]=lag
            {
                const float4* pp = (const float4*)(xrow + (size_t)tt * 8);
                float4 u0 = pp[0], u1 = pp[1];
                xv[0] = packf2(u0.x, u0.y); xv[1] = packf2(u0.z, u0.w);
                xv[2] = packf2(u1.x, u1.y); xv[3] = packf2(u1.z, u1.w);
                if (dir) {
                    const float4* qq = (const float4*)(xrow + (size_t)(tt - 1) * 8);
                    float4 v0 = qq[0], v1 = qq[1];
                    xv[4] = packf2(v0.x, v0.y); xv[5] = packf2(v0.z, v0.w);
                    xv[6] = packf2(v1.x, v1.y); xv[7] = packf2(v1.z, v1.w);
                } else {
#pragma unroll
                    for (int d = 4; d < 8; ++d) xv[d] = 0u;
                }
            }

            for (int s = 0; s < T_TOTAL; ++s) {
                float a[4] = {bias[0], bias[1], bias[2], bias[3]};
                xdots(xv, a);

                // prefetch next fresh row while the dots retire
                const int li = dir ? (tt - 2) : (tt + 1);
                const bool ld = (li >= 0) && (li < T_TOTAL);
                float4 n0 = {0, 0, 0, 0}, n1 = {0, 0, 0, 0};
                if (ld) {
                    const float4* pp = (const float4*)(xrow + (size_t)li * 8);
                    n0 = pp[0];
                    n1 = pp[1];
                }

                emit(s, a);

                uint32_t np[4] = {packf2(n0.x, n0.y), packf2(n0.z, n0.w),
                                  packf2(n1.x, n1.y), packf2(n1.z, n1.w)};
                if (dir == 0) {
#pragma unroll
                    for (int d = 0; d < 4; ++d) { xv[4 + d] = xv[d]; xv[d] = np[d]; }
                } else {
#pragma unroll
                    for (int d = 0; d < 4; ++d) {
                        xv[d] = xv[4 + d];
                        xv[4 + d] = ld ? np[d] : 0u;
                    }
                }
                tt += tstep;
            }
        } else {
            const ptrdiff_t ipstep = (ptrdiff_t)tstep * (B_TOTAL * ND);
            const uint32_t* ip = (const uint32_t*)inbuf + (size_t)tt * (B_TOTAL * ND) + (size_t)bs * ND;

            uint32_t xq0[ND], xq1[ND];
#pragma unroll
            for (int d = 0; d < ND; ++d) xq0[d] = ip[d];
            ip += ipstep;
#pragma unroll
            for (int d = 0; d < ND; ++d) xq1[d] = ip[d];
            ip += ipstep;

            auto pstep = [&](uint32_t* xc, int s, bool pf) {
                float a[4] = {bias[0], bias[1], bias[2], bias[3]};
                xdots(xc, a);
                if (pf) {
#pragma unroll
                    for (int d = 0; d < ND; ++d) xc[d] = ip[d];
                    ip += ipstep;
                }
                emit(s, a);
            };

            for (int s = 0; s < T_TOTAL; s += 2) {
                pstep(xq0, s, s + 2 < T_TOTAL);
                pstep(xq1, s + 1, s + 3 < T_TOTAL);
            }
        }
    } else {
        // ------------------------- consumer -------------------------
        const float* w_hh = dir ? whhb : whhf;
        f16x2 whh2[4][NH];
#pragma unroll
        for (int q = 0; q < 4; ++q) {
            const int r = q * H + j;
#pragma unroll
            for (int k = 0; k < NH; ++k) {
                f16x2 t;
                t.x = (_Float16)w_hh[r * H + 2 * k];
                t.y = (_Float16)w_hh[r * H + 2 * k + 1];
                whh2[q][k] = t;
            }
        }

        __half* op = nullptr;
        ptrdiff_t opstep = 0;
        if constexpr (STORE_ALL) {
            op = outbuf + (size_t)tt * (B_TOTAL * 2 * H) + (size_t)bs * (2 * H) + dir * H + j;
            opstep = (ptrdiff_t)tstep * (B_TOTAL * 2 * H);
        }

        float c = 0.0f;
        float hlast = 0.0f;

        // prime: hd (zeros) + slot-0 prefetch
        uint32_t hd[NH];
#pragma unroll
        for (int k = 0; k < NH; ++k) hd[k] = hsm[g][k];

        int   fl_p;
        float pa0, pa1, pa2, pa3;
        {
            volatile float* pn = vgx + (size_t)0 * 256 + lane * 4;
            fl_p = vflg[0];
            pa0 = pn[0]; pa1 = pn[1]; pa2 = pn[2]; pa3 = pn[3];
        }

        for (int s = 0; s < T_TOTAL; ++s) {
            const int slot = s & (SLOTS - 1);
            float a0 = pa0, a1 = pa1, a2 = pa2, a3 = pa3;
            int fl = fl_p;
            if (fl != s + 1) {   // producer behind: re-poll (rare steady-state)
                volatile float* p = vgx + (size_t)slot * 256 + lane * 4;
                do {
                    fl = vflg[slot];
                    a0 = p[0]; a1 = p[1]; a2 = p[2]; a3 = p[3];
                } while (fl != s + 1);
            }
            // prefetch slot s+1 (checked next iteration; latency off the chain)
            {
                const int ns = (s + 1) & (SLOTS - 1);
                volatile float* pn = vgx + (size_t)ns * 256 + lane * 4;
                fl_p = vflg[ns];
                pa0 = pn[0]; pa1 = pn[1]; pa2 = pn[2]; pa3 = pn[3];
            }

            // h-dots (hd issued at end of previous iteration)
#pragma unroll
            for (int k = 0; k < NH; ++k) {
                a0 = dot2acc(hd[k], whh2[0][k], a0);
                a1 = dot2acc(hd[k], whh2[1][k], a1);
                a2 = dot2acc(hd[k], whh2[2][k], a2);
                a3 = dot2acc(hd[k], whh2[3][k], a3);
            }
            const float iv = sigm_(a0);
            const float fv = sigm_(a1);
            const float gv = tanh_(a2);
            const float ov = sigm_(a3);
            c = __builtin_fmaf(fv, c, iv * gv);
            const float h = ov * tanh_(c);
            ((__half*)&hsm[g][0])[j] = __float2half(h);
            wavebar();
            // re-issue hd for the next step right after the write (in-order DS)
#pragma unroll
            for (int k = 0; k < NH; ++k) hd[k] = hsm[g][k];

            if constexpr (STORE_ALL) {
                if (valid) *op = __float2half(h);
                op += opstep;
            } else {
                hlast = h;
            }
            if ((s & 7) == 7) {
                if (lane == 0) *vcons = s;
            }
        }

        if constexpr (!STORE_ALL) {
            if (valid) lasth[b * H + j] = hlast;
        }
    }
}

// L4 backward needed only at t=T-1 (single step from zero state) + FC + sigmoid.
__global__ void final_kernel(const __half* __restrict__ l3out,  // [T][B][20] f16
                             const float* __restrict__ hf4,     // [B][10]
                             const float* __restrict__ w_ih,    // w4b_ih [40][20]
                             const float* __restrict__ b_ih,
                             const float* __restrict__ b_hh,
                             const float* __restrict__ fc_w,    // [20]
                             const float* __restrict__ fc_b,
                             float* __restrict__ out)           // [B]
{
    const int b = blockIdx.x * blockDim.x + threadIdx.x;
    if (b >= B_TOTAL) return;

    float in4[20];
    const __half* p = l3out + (size_t)(T_TOTAL - 1) * (B_TOTAL * 20) + (size_t)b * 20;
#pragma unroll
    for (int i = 0; i < 20; ++i) in4[i] = __half2float(p[i]);

    float z = fc_b[0];
#pragma unroll
    for (int k = 0; k < 10; ++k) z += fc_w[k] * hf4[b * 10 + k];

#pragma unroll
    for (int k = 0; k < 10; ++k) {
        float gi = b_ih[k]      + b_hh[k];
        float gg = b_ih[20 + k] + b_hh[20 + k];
        float go = b_ih[30 + k] + b_hh[30 + k];
#pragma unroll
        for (int i = 0; i < 20; ++i) {
            const float xi = in4[i];
            gi += w_ih[k * 20 + i]        * xi;
            gg += w_ih[(20 + k) * 20 + i] * xi;
            go += w_ih[(30 + k) * 20 + i] * xi;
        }
        const float cc = sigm_(gi) * tanh_(gg);
        const float hb = sigm_(go) * tanh_(cc);
        z += fc_w[10 + k] * hb;
    }
    out[b] = sigm_(z);
}

extern "C" void kernel_launch(void* const* d_in, const int* in_sizes, int n_in,
                              void* d_out, int out_size, void* d_ws, size_t ws_size,
                              hipStream_t stream) {
    const float* x = (const float*)d_in[0];
    auto W = [&](int li, int dr, int k) -> const float* {
        return (const float*)d_in[1 + (li - 1) * 8 + dr * 4 + k];
    };
    const float* fc_w = (const float*)d_in[33];
    const float* fc_b = (const float*)d_in[34];
    float* out = (float*)d_out;

    // ws: buf0 [T][B][40] f16 (80MB), buf1 [T][B][40] f16 (80MB), hf4 [B][10] f32
    __half* buf0 = (__half*)d_ws;
    __half* buf1 = buf0 + (size_t)T_TOTAL * B_TOTAL * 40;
    float* hf4 = (float*)(buf1 + (size_t)T_TOTAL * B_TOTAL * 40);

    // Layer 1: DIN=16 (x + lag), H=20 -> buf0 [T][B][40]
    lstm_pc<16, 20, true, true><<<dim3(342, 2, 1), dim3(64, 2, 1), 0, stream>>>(
        x, nullptr,
        W(1,0,0), W(1,0,1), W(1,0,2), W(1,0,3),
        W(1,1,0), W(1,1,1), W(1,1,2), W(1,1,3),
        buf0, nullptr);

    // Layer 2: DIN=40, H=20 -> buf1 [T][B][40]
    lstm_pc<40, 20, false, true><<<dim3(342, 2, 1), dim3(64, 2, 1), 0, stream>>>(
        nullptr, buf0,
        W(2,0,0), W(2,0,1), W(2,0,2), W(2,0,3),
        W(2,1,0), W(2,1,1), W(2,1,2), W(2,1,3),
        buf1, nullptr);

    // Layer 3: DIN=40, H=10 -> buf0 [T][B][20]
    lstm_pc<40, 10, false, true><<<dim3(171, 2, 1), dim3(64, 2, 1), 0, stream>>>(
        nullptr, buf1,
        W(3,0,0), W(3,0,1), W(3,0,2), W(3,0,3),
        W(3,1,0), W(3,1,1), W(3,1,2), W(3,1,3),
        buf0, nullptr);

    // Layer 4 forward only: DIN=20, H=10 -> hf4 [B][10]
    lstm_pc<20, 10, false, false><<<dim3(171, 1, 1), dim3(64, 2, 1), 0, stream>>>(
        nullptr, buf0,
        W(4,0,0), W(4,0,1), W(4,0,2), W(4,0,3),
        W(4,0,0), W(4,0,1), W(4,0,2), W(4,0,3), // dir=1 never launched
        nullptr, hf4);

    // L4 backward single step + FC + sigmoid
    final_kernel<<<dim3(4, 1, 1), 256, 0, stream>>>(
        buf0, hf4, W(4,1,0), W(4,1,2), W(4,1,3), fc_w, fc_b, out);
}

// Round 4
// 1665.305 us; speedup vs baseline: 1.7415x; 1.7415x over previous
//
#include <hip/hip_runtime.h>
#include <hip/hip_fp16.h>
#include <stdint.h>

#define B_TOTAL 1024
#define T_TOTAL 1024
#define LOG2E 1.44269504088896f

typedef _Float16 f16x2 __attribute__((ext_vector_type(2)));

__device__ __forceinline__ float dot2w(uint32_t xw, uint32_t ww, float acc) {
#if __has_builtin(__builtin_amdgcn_fdot2)
    return __builtin_amdgcn_fdot2(__builtin_bit_cast(f16x2, xw),
                                  __builtin_bit_cast(f16x2, ww), acc, false);
#else
    f16x2 xv = __builtin_bit_cast(f16x2, xw);
    f16x2 wv = __builtin_bit_cast(f16x2, ww);
    return acc + (float)xv.x * (float)wv.x + (float)xv.y * (float)wv.y;
#endif
}

__device__ __forceinline__ uint32_t packf2(float a, float b) {
    f16x2 t;
    t.x = (_Float16)a;
    t.y = (_Float16)b;
    return __builtin_bit_cast(uint32_t, t);
}

__device__ __forceinline__ float sigm_(float z) {
    float e = __builtin_amdgcn_exp2f(-LOG2E * z);
    return __builtin_amdgcn_rcpf(1.0f + e);
}
__device__ __forceinline__ float tanh_(float z) {
    float e = __builtin_amdgcn_exp2f((2.0f * LOG2E) * z);
    float r = __builtin_amdgcn_rcpf(1.0f + e);
    return __builtin_fmaf(-2.0f, r, 1.0f);
}

__device__ __forceinline__ void wavebar() {
#if __has_builtin(__builtin_amdgcn_wave_barrier)
    __builtin_amdgcn_wave_barrier();
#endif
}

// =================== single-wave LSTM scan, round 4 ===================
// History: r0/r1 single-wave = 510us/dispatch at VGPR=92/132 — allocator
// REMATERIALIZED the "register" weight arrays (per-step L1-hot reloads,
// FETCH unchanged, 66% stall). r2/r3 producer-consumer split failed:
// r3's LDS weights had 8-way bank conflicts (6.1e7 conflict-cycles; row
// stride 20 dwords), r2's producer hit the same remat trap.
// This round: single wave again, with
//  (1) weights pinned in VGPRs via opaque inline-asm "+v" defs (cannot be
//      rematerialized; budget 256 via waves_per_eu(1,1)),
//  (2) input staged through a double-buffered LDS chunk (global->reg at
//      chunk start, reg->LDS at chunk middle; per-step ds_read_b128
//      BROADCAST reads: group bases {20g,10g,4g} mod 32 -> disjoint bank
//      spans -> conflict-free, unlike r3's per-j weight rows),
//  (3) round-0 h broadcast: hd issued at step top, hidden under x-dots.
template <int DIN, int H, bool LAYER1, bool STORE_ALL>
__global__ void __launch_bounds__(64)
__attribute__((amdgpu_waves_per_eu(1, 1))) lstm_scan(
    const float* __restrict__ x,              // LAYER1: [B][T][8] f32
    const __half* __restrict__ inbuf,         // layers>1: [T][B][DIN] f16
    const float* __restrict__ wihf, const float* __restrict__ whhf,
    const float* __restrict__ bihf, const float* __restrict__ bhhf,
    const float* __restrict__ wihb, const float* __restrict__ whhb,
    const float* __restrict__ bihb, const float* __restrict__ bhhb,
    __half* __restrict__ outbuf,              // STORE_ALL: [T][B][2H] f16
    float* __restrict__ lasth)                // !STORE_ALL: [B][H] f32
{
    constexpr int GPW    = 64 / H;     // batch groups per wave (3 or 6)
    constexpr int ND     = DIN / 2;    // input dwords (f16 pairs)
    constexpr int NH     = H / 2;      // h dwords
    constexpr int HS_DW  = (H == 20) ? 12 : 8;
    constexpr int CHUNK  = (GPW == 3) ? 16 : 8;   // steps staged per chunk
    constexpr int NCHUNK = T_TOTAL / CHUNK;
    constexpr int NDX    = LAYER1 ? 4 : ND;       // LDS dwords per staged row
    constexpr int XROWS  = LAYER1 ? (CHUNK + 1) : CHUNK;  // +1 lag row for L1
    constexpr int XWORDS = XROWS * GPW * NDX;
    constexpr int NLOAD  = (XWORDS + 63) / 64;

    const int dir  = blockIdx.y;
    const int lane = threadIdx.x;
    const int g    = lane / H;
    const int j    = lane - g * H;
    const int b    = blockIdx.x * GPW + g;
    const bool valid = (g < GPW) && (b < B_TOTAL);
    const int bs   = valid ? b : (B_TOTAL - 1);

    const float* w_ih = dir ? wihb : wihf;
    const float* w_hh = dir ? whhb : whhf;
    const float* b_ih = dir ? bihb : bihf;
    const float* b_hh = dir ? bhhb : bhhf;

    __shared__ uint32_t xsm[2 * XWORDS];
    __shared__ uint32_t hsm[GPW + 1][HS_DW];

    // ---- weights for all 4 gates of unit j -> registers, then PIN ----
    uint32_t wih2[4][ND];
    uint32_t whh2[4][NH];
    float bias[4];
#pragma unroll
    for (int q = 0; q < 4; ++q) {
        const int r = q * H + j;
#pragma unroll
        for (int d = 0; d < ND; ++d)
            wih2[q][d] = packf2(w_ih[r * DIN + 2 * d], w_ih[r * DIN + 2 * d + 1]);
#pragma unroll
        for (int k = 0; k < NH; ++k)
            whh2[q][k] = packf2(w_hh[r * H + 2 * k], w_hh[r * H + 2 * k + 1]);
        bias[q] = b_ih[r] + b_hh[r];
    }
    // Opaque defs: the allocator can no longer rematerialize these from
    // global memory inside the scan loop (r0/r1's hidden 800 cy/step).
#pragma unroll
    for (int q = 0; q < 4; ++q) {
#pragma unroll
        for (int d = 0; d < ND; ++d) asm volatile("" : "+v"(wih2[q][d]));
#pragma unroll
        for (int k = 0; k < NH; ++k) asm volatile("" : "+v"(whh2[q][k]));
        asm volatile("" : "+v"(bias[q]));
    }

    // ---- chunked input staging helpers ----
    uint32_t greg[NLOAD];

    auto stage_load = [&](int c) {
        const int sbase = c * CHUNK;
#pragma unroll
        for (int i = 0; i < NLOAD; ++i) {
            const int idx = lane + 64 * i;
            uint32_t v = 0;
            if (idx < XWORDS) {
                const int row = idx / (GPW * NDX);
                const int rem = idx - row * (GPW * NDX);
                const int r   = rem / NDX;
                const int d   = rem - r * NDX;
                const int br  = blockIdx.x * GPW + r;
                int t;
                if constexpr (LAYER1)
                    t = dir ? (T_TOTAL - 1 - sbase) - row : (sbase - 1) + row;
                else
                    t = dir ? (T_TOTAL - 1) - (sbase + row) : sbase + row;
                if (t >= 0 && t < T_TOTAL && br < B_TOTAL) {
                    if constexpr (LAYER1) {
                        const float2 p = ((const float2*)(x + (size_t)br * (T_TOTAL * 8) +
                                                          (size_t)t * 8))[d];
                        v = packf2(p.x, p.y);
                    } else {
                        v = ((const uint32_t*)inbuf)[(size_t)t * (B_TOTAL * ND) +
                                                     (size_t)br * ND + d];
                    }
                }
            }
            greg[i] = v;
        }
    };
    auto stage_write = [&](int buf) {
#pragma unroll
        for (int i = 0; i < NLOAD; ++i) {
            const int idx = lane + 64 * i;
            if (idx < XWORDS) xsm[buf * XWORDS + idx] = greg[i];
        }
    };

    // per-step LDS row reads (broadcast within group; disjoint bank spans)
    auto xread = [&](int buf, int row, uint32_t* dst) {
        const uint32_t* p = &xsm[buf * XWORDS + row * (GPW * NDX) + g * NDX];
        if constexpr (NDX % 4 == 0) {
#pragma unroll
            for (int d = 0; d < NDX; d += 4) {
                uint4 v = *(const uint4*)(p + d);
                dst[d] = v.x; dst[d + 1] = v.y; dst[d + 2] = v.z; dst[d + 3] = v.w;
            }
        } else {
#pragma unroll
            for (int d = 0; d < NDX; d += 2) {
                uint2 v = *(const uint2*)(p + d);
                dst[d] = v.x; dst[d + 1] = v.y;
            }
        }
    };

    const int tstep = dir ? -1 : 1;
    int tt = dir ? (T_TOTAL - 1) : 0;

    __half* op = nullptr;
    ptrdiff_t opstep = 0;
    if constexpr (STORE_ALL) {
        op = outbuf + (size_t)tt * (B_TOTAL * 2 * H) + (size_t)bs * (2 * H) + dir * H + j;
        opstep = (ptrdiff_t)tstep * (B_TOTAL * 2 * H);
    }

    float c_st = 0.0f;
    float hlast = 0.0f;
    ((__half*)&hsm[g][0])[j] = __float2half(0.0f);
    wavebar();

    // prime chunk 0
    stage_load(0);
    stage_write(0);

    auto tail = [&](const uint32_t* hd, float a0, float a1, float a2, float a3) {
#pragma unroll
        for (int k = 0; k < NH; ++k) {
            a0 = dot2w(hd[k], whh2[0][k], a0);
            a1 = dot2w(hd[k], whh2[1][k], a1);
            a2 = dot2w(hd[k], whh2[2][k], a2);
            a3 = dot2w(hd[k], whh2[3][k], a3);
        }
        const float iv = sigm_(a0);
        const float fv = sigm_(a1);
        const float gv = tanh_(a2);
        const float ov = sigm_(a3);
        c_st = __builtin_fmaf(fv, c_st, iv * gv);
        const float h = ov * tanh_(c_st);
        ((__half*)&hsm[g][0])[j] = __float2half(h);
        wavebar();
        if constexpr (STORE_ALL) {
            if (valid) *op = __float2half(h);
            op += opstep;
        } else {
            hlast = h;
        }
        tt += tstep;
    };

    if constexpr (LAYER1) {
        uint32_t cur4[4], lag4[4], nrow[4];
        xread(0, dir ? 0 : 1, cur4);
        xread(0, dir ? 1 : 0, lag4);

        int buf = 0;
        for (int c = 0; c < NCHUNK; ++c) {
#pragma unroll
            for (int k = 0; k < CHUNK; ++k) {
                uint32_t hd[NH];
#pragma unroll
                for (int q = 0; q < NH; ++q) hd[q] = hsm[g][q];

                if (k == 0 && c + 1 < NCHUNK) stage_load(c + 1);

                float a0 = bias[0], a1 = bias[1], a2 = bias[2], a3 = bias[3];
#pragma unroll
                for (int d = 0; d < 4; ++d) {
                    a0 = dot2w(cur4[d], wih2[0][d], a0);
                    a1 = dot2w(cur4[d], wih2[1][d], a1);
                    a2 = dot2w(cur4[d], wih2[2][d], a2);
                    a3 = dot2w(cur4[d], wih2[3][d], a3);
                }
#pragma unroll
                for (int d = 0; d < 4; ++d) {
                    a0 = dot2w(lag4[d], wih2[0][4 + d], a0);
                    a1 = dot2w(lag4[d], wih2[1][4 + d], a1);
                    a2 = dot2w(lag4[d], wih2[2][4 + d], a2);
                    a3 = dot2w(lag4[d], wih2[3][4 + d], a3);
                }

                // prefetch the one new packed row for step k+1
                if (k < CHUNK - 1) xread(buf, k + 2, nrow);
                else               xread(buf ^ 1, 1, nrow);

                if (k == CHUNK / 2 && c + 1 < NCHUNK) stage_write(buf ^ 1);

                tail(hd, a0, a1, a2, a3);

                if (dir == 0) {
#pragma unroll
                    for (int d = 0; d < 4; ++d) { lag4[d] = cur4[d]; cur4[d] = nrow[d]; }
                } else {
#pragma unroll
                    for (int d = 0; d < 4; ++d) { cur4[d] = lag4[d]; lag4[d] = nrow[d]; }
                }
            }
            buf ^= 1;
        }
    } else {
        uint32_t xcA[ND], xcB[ND];
        xread(0, 0, xcA);

        int buf = 0;
        for (int c = 0; c < NCHUNK; ++c) {
#pragma unroll
            for (int k = 0; k < CHUNK; ++k) {
                const uint32_t* xc = (k & 1) ? xcB : xcA;
                uint32_t*       xn = (k & 1) ? xcA : xcB;

                uint32_t hd[NH];
#pragma unroll
                for (int q = 0; q < NH; ++q) hd[q] = hsm[g][q];

                if (k == 0 && c + 1 < NCHUNK) stage_load(c + 1);

                float a0 = bias[0], a1 = bias[1], a2 = bias[2], a3 = bias[3];
#pragma unroll
                for (int d = 0; d < ND; ++d) {
                    a0 = dot2w(xc[d], wih2[0][d], a0);
                    a1 = dot2w(xc[d], wih2[1][d], a1);
                    a2 = dot2w(xc[d], wih2[2][d], a2);
                    a3 = dot2w(xc[d], wih2[3][d], a3);
                }

                // prefetch next step's input row
                if (k < CHUNK - 1) xread(buf, k + 1, xn);
                else               xread(buf ^ 1, 0, xn);

                if (k == CHUNK / 2 && c + 1 < NCHUNK) stage_write(buf ^ 1);

                tail(hd, a0, a1, a2, a3);
            }
            buf ^= 1;
        }
    }

    if constexpr (!STORE_ALL) {
        if (valid) lasth[b * H + j] = hlast;
    }
}

// L4 backward needed only at t=T-1 (single step from zero state) + FC + sigmoid.
__global__ void final_kernel(const __half* __restrict__ l3out,  // [T][B][20] f16
                             const float* __restrict__ hf4,     // [B][10]
                             const float* __restrict__ w_ih,    // w4b_ih [40][20]
                             const float* __restrict__ b_ih,
                             const float* __restrict__ b_hh,
                             const float* __restrict__ fc_w,    // [20]
                             const float* __restrict__ fc_b,
                             float* __restrict__ out)           // [B]
{
    const int b = blockIdx.x * blockDim.x + threadIdx.x;
    if (b >= B_TOTAL) return;

    float in4[20];
    const __half* p = l3out + (size_t)(T_TOTAL - 1) * (B_TOTAL * 20) + (size_t)b * 20;
#pragma unroll
    for (int i = 0; i < 20; ++i) in4[i] = __half2float(p[i]);

    float z = fc_b[0];
#pragma unroll
    for (int k = 0; k < 10; ++k) z += fc_w[k] * hf4[b * 10 + k];

#pragma unroll
    for (int k = 0; k < 10; ++k) {
        float gi = b_ih[k]      + b_hh[k];
        float gg = b_ih[20 + k] + b_hh[20 + k];
        float go = b_ih[30 + k] + b_hh[30 + k];
#pragma unroll
        for (int i = 0; i < 20; ++i) {
            const float xi = in4[i];
            gi += w_ih[k * 20 + i]        * xi;
            gg += w_ih[(20 + k) * 20 + i] * xi;
            go += w_ih[(30 + k) * 20 + i] * xi;
        }
        const float cc = sigm_(gi) * tanh_(gg);
        const float hb = sigm_(go) * tanh_(cc);
        z += fc_w[10 + k] * hb;
    }
    out[b] = sigm_(z);
}

extern "C" void kernel_launch(void* const* d_in, const int* in_sizes, int n_in,
                              void* d_out, int out_size, void* d_ws, size_t ws_size,
                              hipStream_t stream) {
    const float* x = (const float*)d_in[0];
    auto W = [&](int li, int dr, int k) -> const float* {
        return (const float*)d_in[1 + (li - 1) * 8 + dr * 4 + k];
    };
    const float* fc_w = (const float*)d_in[33];
    const float* fc_b = (const float*)d_in[34];
    float* out = (float*)d_out;

    // ws: buf0 [T][B][40] f16 (80MB), buf1 [T][B][40] f16 (80MB), hf4 [B][10] f32
    __half* buf0 = (__half*)d_ws;
    __half* buf1 = buf0 + (size_t)T_TOTAL * B_TOTAL * 40;
    float* hf4 = (float*)(buf1 + (size_t)T_TOTAL * B_TOTAL * 40);

    // Layer 1: DIN=16 (x + lag), H=20 -> buf0 [T][B][40]
    lstm_scan<16, 20, true, true><<<dim3(342, 2, 1), 64, 0, stream>>>(
        x, nullptr,
        W(1,0,0), W(1,0,1), W(1,0,2), W(1,0,3),
        W(1,1,0), W(1,1,1), W(1,1,2), W(1,1,3),
        buf0, nullptr);

    // Layer 2: DIN=40, H=20 -> buf1 [T][B][40]
    lstm_scan<40, 20, false, true><<<dim3(342, 2, 1), 64, 0, stream>>>(
        nullptr, buf0,
        W(2,0,0), W(2,0,1), W(2,0,2), W(2,0,3),
        W(2,1,0), W(2,1,1), W(2,1,2), W(2,1,3),
        buf1, nullptr);

    // Layer 3: DIN=40, H=10 -> buf0 [T][B][20]
    lstm_scan<40, 10, false, true><<<dim3(171, 2, 1), 64, 0, stream>>>(
        nullptr, buf1,
        W(3,0,0), W(3,0,1), W(3,0,2), W(3,0,3),
        W(3,1,0), W(3,1,1), W(3,1,2), W(3,1,3),
        buf0, nullptr);

    // Layer 4 forward only: DIN=20, H=10 -> hf4 [B][10]
    lstm_scan<20, 10, false, false><<<dim3(171, 1, 1), 64, 0, stream>>>(
        nullptr, buf0,
        W(4,0,0), W(4,0,1), W(4,0,2), W(4,0,3),
        W(4,0,0), W(4,0,1), W(4,0,2), W(4,0,3), // dir=1 never launched
        nullptr, hf4);

    // L4 backward single step + FC + sigmoid
    final_kernel<<<dim3(4, 1, 1), 256, 0, stream>>>(
        buf0, hf4, W(4,1,0), W(4,1,2), W(4,1,3), fc_w, fc_b, out);
}

// Round 5
// 1655.862 us; speedup vs baseline: 1.7515x; 1.0057x over previous
//
#include <hip/hip_runtime.h>
#include <hip/hip_fp16.h>
#include <stdint.h>

#define B_TOTAL 1024
#define T_TOTAL 1024
#define LOG2E 1.44269504088896f

typedef _Float16 f16x2 __attribute__((ext_vector_type(2)));

__device__ __forceinline__ float dot2w(uint32_t xw, uint32_t ww, float acc) {
#if __has_builtin(__builtin_amdgcn_fdot2)
    return __builtin_amdgcn_fdot2(__builtin_bit_cast(f16x2, xw),
                                  __builtin_bit_cast(f16x2, ww), acc, false);
#else
    f16x2 xv = __builtin_bit_cast(f16x2, xw);
    f16x2 wv = __builtin_bit_cast(f16x2, ww);
    return acc + (float)xv.x * (float)wv.x + (float)xv.y * (float)wv.y;
#endif
}

__device__ __forceinline__ uint32_t packf2(float a, float b) {
    f16x2 t;
    t.x = (_Float16)a;
    t.y = (_Float16)b;
    return __builtin_bit_cast(uint32_t, t);
}

__device__ __forceinline__ float sigm_(float z) {
    float e = __builtin_amdgcn_exp2f(-LOG2E * z);
    return __builtin_amdgcn_rcpf(1.0f + e);
}
__device__ __forceinline__ float tanh_(float z) {
    float e = __builtin_amdgcn_exp2f((2.0f * LOG2E) * z);
    float r = __builtin_amdgcn_rcpf(1.0f + e);
    return __builtin_fmaf(-2.0f, r, 1.0f);
}

__device__ __forceinline__ void wavebar() {
#if __has_builtin(__builtin_amdgcn_wave_barrier)
    __builtin_amdgcn_wave_barrier();
#endif
}

// ====================== projection pass (round 5) ======================
// Gx[dir][row][4H] f16 = in[row][:] @ W_ih_dir^T, element order per row:
// o = j*4 + q (unit-major) so the scan lane (g,j) reads its 4 gates as ONE
// b64 load. Massively parallel over rows=T*B: runs on the 92% of the chip
// the serial scan leaves idle. Weights transposed in LDS (wt[d][o]) so the
// inner loop is LDS-broadcast xin + consecutive-o wt reads.
template <int DIN, int H, int NDIR, bool L1X>
__global__ void __launch_bounds__(256) proj_kernel(
    const float* __restrict__ x,        // L1X: [B][T][8] f32
    const __half* __restrict__ inbuf,   // else: [ROWS][DIN] f16
    const float* __restrict__ w0,       // W_ih fwd [4H][DIN] f32
    const float* __restrict__ w1,       // W_ih bwd
    __half* __restrict__ g0,            // Gx fwd [ROWS][4H] f16
    __half* __restrict__ g1)            // Gx bwd
{
    constexpr int NDW   = DIN / 2;
    constexpr int O4H   = 4 * H;
    constexpr int OUT   = NDIR * O4H;
    constexpr int RPB   = 16;           // rows per tile
    constexpr int TPR   = 16;           // threads per row
    constexpr int OPT   = (OUT + TPR - 1) / TPR;
    constexpr int TILES = 8;            // tiles per block (amortize wt stage)
    constexpr int DWR   = O4H / 2;      // dwords per dir-row

    __shared__ uint32_t wt[NDW][OUT];
    __shared__ uint32_t xin[RPB * NDW];
    __shared__ uint32_t osm[RPB][OUT / 2];

    const int tid = threadIdx.x;

    // stage transposed weights once per block
    for (int idx = tid; idx < NDW * OUT; idx += 256) {
        const int d  = idx / OUT;
        const int o  = idx - d * OUT;
        const int dr = o / O4H;
        const int oo = o - dr * O4H;
        const int jj = oo >> 2;
        const int qq = oo & 3;
        const float* w = dr ? w1 : w0;
        const int row = qq * H + jj;
        wt[d][o] = packf2(w[row * DIN + 2 * d], w[row * DIN + 2 * d + 1]);
    }

    const int rr = tid >> 4;
    const int li = tid & 15;

    for (int tile = 0; tile < TILES; ++tile) {
        const int r0 = (blockIdx.x * TILES + tile) * RPB;
        __syncthreads();   // wt ready / prev tile's osm consumed

        if constexpr (L1X) {
            for (int idx = tid; idx < RPB * NDW; idx += 256) {
                const int r  = r0 + idx / NDW;
                const int d  = idx % NDW;
                const int bb = r >> 10;            // T_TOTAL = 1024
                const int t  = r & (T_TOTAL - 1);
                float2 v = {0.f, 0.f};
                if (d < 4) {
                    v = ((const float2*)(x + ((size_t)bb * T_TOTAL + t) * 8))[d];
                } else if (t > 0) {
                    v = ((const float2*)(x + ((size_t)bb * T_TOTAL + t - 1) * 8))[d - 4];
                }
                xin[idx] = packf2(v.x, v.y);
            }
        } else {
            const uint32_t* src = (const uint32_t*)inbuf + (size_t)r0 * NDW;
            for (int idx = tid; idx < RPB * NDW; idx += 256)
                xin[idx] = src[idx];
        }
        __syncthreads();

        float acc[OPT];
#pragma unroll
        for (int oi = 0; oi < OPT; ++oi) acc[oi] = 0.f;
#pragma unroll
        for (int d = 0; d < NDW; ++d) {
            const uint32_t xv = xin[rr * NDW + d];
#pragma unroll
            for (int oi = 0; oi < OPT; ++oi) {
                const int o = li * OPT + oi;
                if (OUT % TPR == 0 || o < OUT)
                    acc[oi] = dot2w(xv, wt[d][o], acc[oi]);
            }
        }
        {
            __half* oh = (__half*)&osm[rr][0];
#pragma unroll
            for (int oi = 0; oi < OPT; ++oi) {
                const int o = li * OPT + oi;
                if (OUT % TPR == 0 || o < OUT) oh[o] = __float2half(acc[oi]);
            }
        }
        __syncthreads();

        for (int idx = tid; idx < RPB * (OUT / 2); idx += 256) {
            const int r   = idx / (OUT / 2);
            const int od  = idx - r * (OUT / 2);
            const int dr  = od / DWR;
            const int odd = od - dr * DWR;
            uint32_t* dst = (uint32_t*)(dr ? g1 : g0);
            dst[(size_t)(r0 + r) * DWR + odd] = osm[r][od];
        }
    }
}

// ======================= lean scan pass (round 5) =======================
// Per step: ONE b64 global Gx load (4-step register ring prefetch, clamped
// addresses at the tail) + 4 cvt/bias + NH*4 h-dots + activations + h LDS
// broadcast. No input staging, no x-dots — those moved to proj_kernel.
// W_hh pinned in VGPRs via opaque asm (r0-r3 remat lesson).
template <int H, bool XMAJOR, bool STORE_ALL>
__global__ void __launch_bounds__(64)
__attribute__((amdgpu_waves_per_eu(1, 1))) lstm_scan2(
    const __half* __restrict__ gxf, const __half* __restrict__ gxb,
    const float* __restrict__ whhf, const float* __restrict__ bihf,
    const float* __restrict__ bhhf,
    const float* __restrict__ whhb, const float* __restrict__ bihb,
    const float* __restrict__ bhhb,
    __half* __restrict__ outbuf,    // STORE_ALL: [T][B][2H] f16
    float* __restrict__ lasth)      // !STORE_ALL: [B][H] f32
{
    constexpr int GPW   = 64 / H;
    constexpr int NH    = H / 2;
    constexpr int HS_DW = (H == 20) ? 12 : 8;
    constexpr int PF    = 4;

    const int dir  = blockIdx.y;
    const int lane = threadIdx.x;
    const int g    = lane / H;
    const int j    = lane - g * H;
    const int b    = blockIdx.x * GPW + g;
    const bool valid = (g < GPW) && (b < B_TOTAL);
    const int bs   = valid ? b : (B_TOTAL - 1);

    const __half* gx  = dir ? gxb : gxf;
    const float* w_hh = dir ? whhb : whhf;
    const float* b_i  = dir ? bihb : bihf;
    const float* b_h  = dir ? bhhb : bhhf;

    __shared__ uint32_t hsm[GPW + 1][HS_DW];

    uint32_t whh2[4][NH];
    float bias[4];
#pragma unroll
    for (int q = 0; q < 4; ++q) {
        const int r = q * H + j;
#pragma unroll
        for (int k = 0; k < NH; ++k)
            whh2[q][k] = packf2(w_hh[r * H + 2 * k], w_hh[r * H + 2 * k + 1]);
        bias[q] = b_i[r] + b_h[r];
    }
#pragma unroll
    for (int q = 0; q < 4; ++q) {
#pragma unroll
        for (int k = 0; k < NH; ++k) asm volatile("" : "+v"(whh2[q][k]));
        asm volatile("" : "+v"(bias[q]));
    }

    const int sgn = dir ? -1 : 1;
    const int t0  = dir ? (T_TOTAL - 1) : 0;
    const uint32_t PSTRIDE = XMAJOR ? (uint32_t)(8 * H)
                                    : (uint32_t)(B_TOTAL * 8 * H);
    const uint32_t jboff = (XMAJOR ? (uint32_t)bs * T_TOTAL * 8 * H
                                   : (uint32_t)bs * 8 * H) + (uint32_t)j * 8;
    const char* gxc = (const char*)gx;

    __half* op = nullptr;
    ptrdiff_t opstep = 0;
    if constexpr (STORE_ALL) {
        op = outbuf + (size_t)t0 * (B_TOTAL * 2 * H) + (size_t)bs * (2 * H) + dir * H + j;
        opstep = (ptrdiff_t)sgn * (B_TOTAL * 2 * H);
    }

    ((__half*)&hsm[g][0])[j] = __float2half(0.0f);
    wavebar();
    uint32_t hd[NH];
#pragma unroll
    for (int k = 0; k < NH; ++k) hd[k] = hsm[g][k];

    uint2 pf[PF];
#pragma unroll
    for (int i = 0; i < PF; ++i) {
        const int tp = t0 + sgn * i;
        pf[i] = *(const uint2*)(gxc + jboff + (uint32_t)tp * PSTRIDE);
    }

    float c_st = 0.0f, hlast = 0.0f;

#define STEP(I)                                                               \
    {                                                                         \
        const uint2 gxv = pf[I];                                              \
        int tp = t0 + sgn * (sb + (I) + PF);                                  \
        tp = tp < 0 ? 0 : (tp > T_TOTAL - 1 ? T_TOTAL - 1 : tp);              \
        pf[I] = *(const uint2*)(gxc + jboff + (uint32_t)tp * PSTRIDE);        \
        const f16x2 p01 = __builtin_bit_cast(f16x2, gxv.x);                   \
        const f16x2 p23 = __builtin_bit_cast(f16x2, gxv.y);                   \
        float a0 = (float)p01.x + bias[0];                                    \
        float a1 = (float)p01.y + bias[1];                                    \
        float a2 = (float)p23.x + bias[2];                                    \
        float a3 = (float)p23.y + bias[3];                                    \
        _Pragma("unroll")                                                     \
        for (int k = 0; k < NH; ++k) {                                        \
            a0 = dot2w(hd[k], whh2[0][k], a0);                                \
            a1 = dot2w(hd[k], whh2[1][k], a1);                                \
            a2 = dot2w(hd[k], whh2[2][k], a2);                                \
            a3 = dot2w(hd[k], whh2[3][k], a3);                                \
        }                                                                     \
        const float iv = sigm_(a0);                                           \
        const float fv = sigm_(a1);                                           \
        const float gv = tanh_(a2);                                           \
        const float ov = sigm_(a3);                                           \
        c_st = __builtin_fmaf(fv, c_st, iv * gv);                             \
        const float h = ov * tanh_(c_st);                                     \
        ((__half*)&hsm[g][0])[j] = __float2half(h);                           \
        wavebar();                                                            \
        _Pragma("unroll")                                                     \
        for (int k = 0; k < NH; ++k) hd[k] = hsm[g][k];                       \
        if constexpr (STORE_ALL) {                                            \
            if (valid) *op = __float2half(h);                                 \
            op += opstep;                                                     \
        } else {                                                              \
            hlast = h;                                                        \
        }                                                                     \
    }

    for (int sb = 0; sb < T_TOTAL; sb += PF) {
        STEP(0) STEP(1) STEP(2) STEP(3)
    }
#undef STEP

    if constexpr (!STORE_ALL) {
        if (valid) lasth[b * H + j] = hlast;
    }
}

// ============ fallback: round-4 fused kernel (proven, 1665 us) ============
template <int DIN, int H, bool LAYER1, bool STORE_ALL>
__global__ void __launch_bounds__(64)
__attribute__((amdgpu_waves_per_eu(1, 1))) lstm_scan_fused(
    const float* __restrict__ x,
    const __half* __restrict__ inbuf,
    const float* __restrict__ wihf, const float* __restrict__ whhf,
    const float* __restrict__ bihf, const float* __restrict__ bhhf,
    const float* __restrict__ wihb, const float* __restrict__ whhb,
    const float* __restrict__ bihb, const float* __restrict__ bhhb,
    __half* __restrict__ outbuf,
    float* __restrict__ lasth)
{
    constexpr int GPW    = 64 / H;
    constexpr int ND     = DIN / 2;
    constexpr int NH     = H / 2;
    constexpr int HS_DW  = (H == 20) ? 12 : 8;
    constexpr int CHUNK  = (GPW == 3) ? 16 : 8;
    constexpr int NCHUNK = T_TOTAL / CHUNK;
    constexpr int NDX    = LAYER1 ? 4 : ND;
    constexpr int XROWS  = LAYER1 ? (CHUNK + 1) : CHUNK;
    constexpr int XWORDS = XROWS * GPW * NDX;
    constexpr int NLOAD  = (XWORDS + 63) / 64;

    const int dir  = blockIdx.y;
    const int lane = threadIdx.x;
    const int g    = lane / H;
    const int j    = lane - g * H;
    const int b    = blockIdx.x * GPW + g;
    const bool valid = (g < GPW) && (b < B_TOTAL);
    const int bs   = valid ? b : (B_TOTAL - 1);

    const float* w_ih = dir ? wihb : wihf;
    const float* w_hh = dir ? whhb : whhf;
    const float* b_ih = dir ? bihb : bihf;
    const float* b_hh = dir ? bhhb : bhhf;

    __shared__ uint32_t xsm[2 * XWORDS];
    __shared__ uint32_t hsm[GPW + 1][HS_DW];

    uint32_t wih2[4][ND];
    uint32_t whh2[4][NH];
    float bias[4];
#pragma unroll
    for (int q = 0; q < 4; ++q) {
        const int r = q * H + j;
#pragma unroll
        for (int d = 0; d < ND; ++d)
            wih2[q][d] = packf2(w_ih[r * DIN + 2 * d], w_ih[r * DIN + 2 * d + 1]);
#pragma unroll
        for (int k = 0; k < NH; ++k)
            whh2[q][k] = packf2(w_hh[r * H + 2 * k], w_hh[r * H + 2 * k + 1]);
        bias[q] = b_ih[r] + b_hh[r];
    }
#pragma unroll
    for (int q = 0; q < 4; ++q) {
#pragma unroll
        for (int d = 0; d < ND; ++d) asm volatile("" : "+v"(wih2[q][d]));
#pragma unroll
        for (int k = 0; k < NH; ++k) asm volatile("" : "+v"(whh2[q][k]));
        asm volatile("" : "+v"(bias[q]));
    }

    uint32_t greg[NLOAD];

    auto stage_load = [&](int c) {
        const int sbase = c * CHUNK;
#pragma unroll
        for (int i = 0; i < NLOAD; ++i) {
            const int idx = lane + 64 * i;
            uint32_t v = 0;
            if (idx < XWORDS) {
                const int row = idx / (GPW * NDX);
                const int rem = idx - row * (GPW * NDX);
                const int r   = rem / NDX;
                const int d   = rem - r * NDX;
                const int br  = blockIdx.x * GPW + r;
                int t;
                if constexpr (LAYER1)
                    t = dir ? (T_TOTAL - 1 - sbase) - row : (sbase - 1) + row;
                else
                    t = dir ? (T_TOTAL - 1) - (sbase + row) : sbase + row;
                if (t >= 0 && t < T_TOTAL && br < B_TOTAL) {
                    if constexpr (LAYER1) {
                        const float2 p = ((const float2*)(x + (size_t)br * (T_TOTAL * 8) +
                                                          (size_t)t * 8))[d];
                        v = packf2(p.x, p.y);
                    } else {
                        v = ((const uint32_t*)inbuf)[(size_t)t * (B_TOTAL * ND) +
                                                     (size_t)br * ND + d];
                    }
                }
            }
            greg[i] = v;
        }
    };
    auto stage_write = [&](int buf) {
#pragma unroll
        for (int i = 0; i < NLOAD; ++i) {
            const int idx = lane + 64 * i;
            if (idx < XWORDS) xsm[buf * XWORDS + idx] = greg[i];
        }
    };
    auto xread = [&](int buf, int row, uint32_t* dst) {
        const uint32_t* p = &xsm[buf * XWORDS + row * (GPW * NDX) + g * NDX];
        if constexpr (NDX % 4 == 0) {
#pragma unroll
            for (int d = 0; d < NDX; d += 4) {
                uint4 v = *(const uint4*)(p + d);
                dst[d] = v.x; dst[d + 1] = v.y; dst[d + 2] = v.z; dst[d + 3] = v.w;
            }
        } else {
#pragma unroll
            for (int d = 0; d < NDX; d += 2) {
                uint2 v = *(const uint2*)(p + d);
                dst[d] = v.x; dst[d + 1] = v.y;
            }
        }
    };

    const int tstep = dir ? -1 : 1;
    int tt = dir ? (T_TOTAL - 1) : 0;

    __half* op = nullptr;
    ptrdiff_t opstep = 0;
    if constexpr (STORE_ALL) {
        op = outbuf + (size_t)tt * (B_TOTAL * 2 * H) + (size_t)bs * (2 * H) + dir * H + j;
        opstep = (ptrdiff_t)tstep * (B_TOTAL * 2 * H);
    }

    float c_st = 0.0f;
    float hlast = 0.0f;
    ((__half*)&hsm[g][0])[j] = __float2half(0.0f);
    wavebar();

    stage_load(0);
    stage_write(0);

    auto tail = [&](const uint32_t* hd, float a0, float a1, float a2, float a3) {
#pragma unroll
        for (int k = 0; k < NH; ++k) {
            a0 = dot2w(hd[k], whh2[0][k], a0);
            a1 = dot2w(hd[k], whh2[1][k], a1);
            a2 = dot2w(hd[k], whh2[2][k], a2);
            a3 = dot2w(hd[k], whh2[3][k], a3);
        }
        const float iv = sigm_(a0);
        const float fv = sigm_(a1);
        const float gv = tanh_(a2);
        const float ov = sigm_(a3);
        c_st = __builtin_fmaf(fv, c_st, iv * gv);
        const float h = ov * tanh_(c_st);
        ((__half*)&hsm[g][0])[j] = __float2half(h);
        wavebar();
        if constexpr (STORE_ALL) {
            if (valid) *op = __float2half(h);
            op += opstep;
        } else {
            hlast = h;
        }
        tt += tstep;
    };

    if constexpr (LAYER1) {
        uint32_t cur4[4], lag4[4], nrow[4];
        xread(0, dir ? 0 : 1, cur4);
        xread(0, dir ? 1 : 0, lag4);

        int buf = 0;
        for (int c = 0; c < NCHUNK; ++c) {
#pragma unroll
            for (int k = 0; k < CHUNK; ++k) {
                uint32_t hd[NH];
#pragma unroll
                for (int q = 0; q < NH; ++q) hd[q] = hsm[g][q];

                if (k == 0 && c + 1 < NCHUNK) stage_load(c + 1);

                float a0 = bias[0], a1 = bias[1], a2 = bias[2], a3 = bias[3];
#pragma unroll
                for (int d = 0; d < 4; ++d) {
                    a0 = dot2w(cur4[d], wih2[0][d], a0);
                    a1 = dot2w(cur4[d], wih2[1][d], a1);
                    a2 = dot2w(cur4[d], wih2[2][d], a2);
                    a3 = dot2w(cur4[d], wih2[3][d], a3);
                }
#pragma unroll
                for (int d = 0; d < 4; ++d) {
                    a0 = dot2w(lag4[d], wih2[0][4 + d], a0);
                    a1 = dot2w(lag4[d], wih2[1][4 + d], a1);
                    a2 = dot2w(lag4[d], wih2[2][4 + d], a2);
                    a3 = dot2w(lag4[d], wih2[3][4 + d], a3);
                }

                if (k < CHUNK - 1) xread(buf, k + 2, nrow);
                else               xread(buf ^ 1, 1, nrow);

                if (k == CHUNK / 2 && c + 1 < NCHUNK) stage_write(buf ^ 1);

                tail(hd, a0, a1, a2, a3);

                if (dir == 0) {
#pragma unroll
                    for (int d = 0; d < 4; ++d) { lag4[d] = cur4[d]; cur4[d] = nrow[d]; }
                } else {
#pragma unroll
                    for (int d = 0; d < 4; ++d) { cur4[d] = lag4[d]; lag4[d] = nrow[d]; }
                }
            }
            buf ^= 1;
        }
    } else {
        uint32_t xcA[ND], xcB[ND];
        xread(0, 0, xcA);

        int buf = 0;
        for (int c = 0; c < NCHUNK; ++c) {
#pragma unroll
            for (int k = 0; k < CHUNK; ++k) {
                const uint32_t* xc = (k & 1) ? xcB : xcA;
                uint32_t*       xn = (k & 1) ? xcA : xcB;

                uint32_t hd[NH];
#pragma unroll
                for (int q = 0; q < NH; ++q) hd[q] = hsm[g][q];

                if (k == 0 && c + 1 < NCHUNK) stage_load(c + 1);

                float a0 = bias[0], a1 = bias[1], a2 = bias[2], a3 = bias[3];
#pragma unroll
                for (int d = 0; d < ND; ++d) {
                    a0 = dot2w(xc[d], wih2[0][d], a0);
                    a1 = dot2w(xc[d], wih2[1][d], a1);
                    a2 = dot2w(xc[d], wih2[2][d], a2);
                    a3 = dot2w(xc[d], wih2[3][d], a3);
                }

                if (k < CHUNK - 1) xread(buf, k + 1, xn);
                else               xread(buf ^ 1, 0, xn);

                if (k == CHUNK / 2 && c + 1 < NCHUNK) stage_write(buf ^ 1);

                tail(hd, a0, a1, a2, a3);
            }
            buf ^= 1;
        }
    }

    if constexpr (!STORE_ALL) {
        if (valid) lasth[b * H + j] = hlast;
    }
}

// L4 backward needed only at t=T-1 (single step from zero state) + FC + sigmoid.
__global__ void final_kernel(const __half* __restrict__ l3out,  // [T][B][20] f16
                             const float* __restrict__ hf4,     // [B][10]
                             const float* __restrict__ w_ih,    // w4b_ih [40][20]
                             const float* __restrict__ b_ih,
                             const float* __restrict__ b_hh,
                             const float* __restrict__ fc_w,    // [20]
                             const float* __restrict__ fc_b,
                             float* __restrict__ out)           // [B]
{
    const int b = blockIdx.x * blockDim.x + threadIdx.x;
    if (b >= B_TOTAL) return;

    float in4[20];
    const __half* p = l3out + (size_t)(T_TOTAL - 1) * (B_TOTAL * 20) + (size_t)b * 20;
#pragma unroll
    for (int i = 0; i < 20; ++i) in4[i] = __half2float(p[i]);

    float z = fc_b[0];
#pragma unroll
    for (int k = 0; k < 10; ++k) z += fc_w[k] * hf4[b * 10 + k];

#pragma unroll
    for (int k = 0; k < 10; ++k) {
        float gi = b_ih[k]      + b_hh[k];
        float gg = b_ih[20 + k] + b_hh[20 + k];
        float go = b_ih[30 + k] + b_hh[30 + k];
#pragma unroll
        for (int i = 0; i < 20; ++i) {
            const float xi = in4[i];
            gi += w_ih[k * 20 + i]        * xi;
            gg += w_ih[(20 + k) * 20 + i] * xi;
            go += w_ih[(30 + k) * 20 + i] * xi;
        }
        const float cc = sigm_(gi) * tanh_(gg);
        const float hb = sigm_(go) * tanh_(cc);
        z += fc_w[10 + k] * hb;
    }
    out[b] = sigm_(z);
}

extern "C" void kernel_launch(void* const* d_in, const int* in_sizes, int n_in,
                              void* d_out, int out_size, void* d_ws, size_t ws_size,
                              hipStream_t stream) {
    const float* x = (const float*)d_in[0];
    auto W = [&](int li, int dr, int k) -> const float* {
        return (const float*)d_in[1 + (li - 1) * 8 + dr * 4 + k];
    };
    const float* fc_w = (const float*)d_in[33];
    const float* fc_b = (const float*)d_in[34];
    float* out = (float*)d_out;

    const size_t ROWS = (size_t)T_TOTAL * B_TOTAL;
    const size_t GXH  = ROWS * 80;   // halfs per Gx dir buffer (max 4H=80)
    const size_t HH   = ROWS * 40;   // halfs per h buffer (max 2H=40)
    const size_t need = (2 * GXH + 2 * HH) * sizeof(__half) +
                        (size_t)B_TOTAL * 10 * sizeof(float);

    if (ws_size >= need) {
        __half* gxf = (__half*)d_ws;
        __half* gxb = gxf + GXH;
        __half* hA  = gxb + GXH;
        __half* hB  = hA + HH;
        float*  hf4 = (float*)(hB + HH);

        // L1: proj from x (+lag), B-major rows
        proj_kernel<16, 20, 2, true><<<dim3(8192), 256, 0, stream>>>(
            x, nullptr, W(1,0,0), W(1,1,0), gxf, gxb);
        lstm_scan2<20, true, true><<<dim3(342, 2), 64, 0, stream>>>(
            gxf, gxb, W(1,0,1), W(1,0,2), W(1,0,3),
                      W(1,1,1), W(1,1,2), W(1,1,3), hA, nullptr);

        // L2
        proj_kernel<40, 20, 2, false><<<dim3(8192), 256, 0, stream>>>(
            nullptr, hA, W(2,0,0), W(2,1,0), gxf, gxb);
        lstm_scan2<20, false, true><<<dim3(342, 2), 64, 0, stream>>>(
            gxf, gxb, W(2,0,1), W(2,0,2), W(2,0,3),
                      W(2,1,1), W(2,1,2), W(2,1,3), hB, nullptr);

        // L3
        proj_kernel<40, 10, 2, false><<<dim3(8192), 256, 0, stream>>>(
            nullptr, hB, W(3,0,0), W(3,1,0), gxf, gxb);
        lstm_scan2<10, false, true><<<dim3(171, 2), 64, 0, stream>>>(
            gxf, gxb, W(3,0,1), W(3,0,2), W(3,0,3),
                      W(3,1,1), W(3,1,2), W(3,1,3), hA, nullptr);

        // L4 forward only
        proj_kernel<20, 10, 1, false><<<dim3(8192), 256, 0, stream>>>(
            nullptr, hA, W(4,0,0), W(4,0,0), gxf, gxf);
        lstm_scan2<10, false, false><<<dim3(171, 1), 64, 0, stream>>>(
            gxf, gxf, W(4,0,1), W(4,0,2), W(4,0,3),
                      W(4,0,1), W(4,0,2), W(4,0,3), nullptr, hf4);

        final_kernel<<<dim3(4), 256, 0, stream>>>(
            hA, hf4, W(4,1,0), W(4,1,2), W(4,1,3), fc_w, fc_b, out);
    } else {
        // -------- fallback: proven round-4 fused path --------
        __half* buf0 = (__half*)d_ws;
        __half* buf1 = buf0 + (size_t)T_TOTAL * B_TOTAL * 40;
        float*  hf4  = (float*)(buf1 + (size_t)T_TOTAL * B_TOTAL * 40);

        lstm_scan_fused<16, 20, true, true><<<dim3(342, 2, 1), 64, 0, stream>>>(
            x, nullptr,
            W(1,0,0), W(1,0,1), W(1,0,2), W(1,0,3),
            W(1,1,0), W(1,1,1), W(1,1,2), W(1,1,3),
            buf0, nullptr);
        lstm_scan_fused<40, 20, false, true><<<dim3(342, 2, 1), 64, 0, stream>>>(
            nullptr, buf0,
            W(2,0,0), W(2,0,1), W(2,0,2), W(2,0,3),
            W(2,1,0), W(2,1,1), W(2,1,2), W(2,1,3),
            buf1, nullptr);
        lstm_scan_fused<40, 10, false, true><<<dim3(171, 2, 1), 64, 0, stream>>>(
            nullptr, buf1,
            W(3,0,0), W(3,0,1), W(3,0,2), W(3,0,3),
            W(3,1,0), W(3,1,1), W(3,1,2), W(3,1,3),
            buf0, nullptr);
        lstm_scan_fused<20, 10, false, false><<<dim3(171, 1, 1), 64, 0, stream>>>(
            nullptr, buf0,
            W(4,0,0), W(4,0,1), W(4,0,2), W(4,0,3),
            W(4,0,0), W(4,0,1), W(4,0,2), W(4,0,3),
            nullptr, hf4);
        final_kernel<<<dim3(4, 1, 1), 256, 0, stream>>>(
            buf0, hf4, W(4,1,0), W(4,1,2), W(4,1,3), fc_w, fc_b, out);
    }
}